// Round 1
// baseline (77.806 us; speedup 1.0000x reference)
//
#include <hip/hip_runtime.h>
#include <hip/hip_bf16.h>

#define NN 2048
#define NH 12
#define HD 32
#define CALL 384   // NH*HD == OUT

typedef float f32x16 __attribute__((ext_vector_type(16)));
typedef _Float16 f16x4 __attribute__((ext_vector_type(4)));

static __device__ __forceinline__ f32x16 mfma8f16(f16x4 a, f16x4 b, f32x16 c) {
    return __builtin_amdgcn_mfma_f32_32x32x8f16(a, b, c, 0, 0, 0);
}

// ---------------------------------------------------------------------------
// GEMM-BT: out[m][n] = sum_k A[m][k] * B[n][k]   (both row-major, contract k)
// MODE 0: A=f32, write outT (f16, transposed [384][2048]), no bias   (h = x W^T)
// MODE 1: A=f32, write outF (f32 [M][384]) + bias                    (res)
// MODE 2: A=f16, write outF (f32 [M][384]) + bias + exact GELU       (final)
// Block: 256 thr, tile 64x64, 4 waves in 2x2, wave tile 32x32, K-chunk 32.
// ---------------------------------------------------------------------------
template <int MODE>
__global__ __launch_bounds__(256) void gemm_bt(
    const float* __restrict__ A, const _Float16* __restrict__ A16,
    const float* __restrict__ B, const float* __restrict__ bias,
    _Float16* __restrict__ outT, float* __restrict__ outF, int Kdim)
{
    __shared__ _Float16 As[64][36];
    __shared__ _Float16 Bs[64][36];
    const int t = threadIdx.x;
    const int w = t >> 6, l = t & 63, g = l >> 5, il = l & 31;
    const int m0 = blockIdx.x * 64, n0 = blockIdx.y * 64;
    const int wr = (w >> 1) * 32, wc = (w & 1) * 32;
    const int ti = t >> 2, seg = t & 3;   // staging: row 0..63, 8-elem segment

    f32x16 acc;
#pragma unroll
    for (int r = 0; r < 16; ++r) acc[r] = 0.f;

    for (int kk = 0; kk < Kdim; kk += 32) {
        __syncthreads();
        // stage A tile [64][32]
        if (MODE == 2) {
            const uint4 v = *reinterpret_cast<const uint4*>(A16 + (size_t)(m0 + ti) * Kdim + kk + seg * 8);
            *reinterpret_cast<uint2*>(&As[ti][seg * 8])     = make_uint2(v.x, v.y);
            *reinterpret_cast<uint2*>(&As[ti][seg * 8 + 4]) = make_uint2(v.z, v.w);
        } else {
            const float* Ap = A + (size_t)(m0 + ti) * Kdim + kk + seg * 8;
            float4 v0 = *reinterpret_cast<const float4*>(Ap);
            float4 v1 = *reinterpret_cast<const float4*>(Ap + 4);
            f16x4 lo = {(_Float16)v0.x, (_Float16)v0.y, (_Float16)v0.z, (_Float16)v0.w};
            f16x4 hi = {(_Float16)v1.x, (_Float16)v1.y, (_Float16)v1.z, (_Float16)v1.w};
            *reinterpret_cast<f16x4*>(&As[ti][seg * 8])     = lo;
            *reinterpret_cast<f16x4*>(&As[ti][seg * 8 + 4]) = hi;
        }
        // stage B tile [64][32] (always fp32 weights)
        {
            const float* Bp = B + (size_t)(n0 + ti) * Kdim + kk + seg * 8;
            float4 v0 = *reinterpret_cast<const float4*>(Bp);
            float4 v1 = *reinterpret_cast<const float4*>(Bp + 4);
            f16x4 lo = {(_Float16)v0.x, (_Float16)v0.y, (_Float16)v0.z, (_Float16)v0.w};
            f16x4 hi = {(_Float16)v1.x, (_Float16)v1.y, (_Float16)v1.z, (_Float16)v1.w};
            *reinterpret_cast<f16x4*>(&Bs[ti][seg * 8])     = lo;
            *reinterpret_cast<f16x4*>(&Bs[ti][seg * 8 + 4]) = hi;
        }
        __syncthreads();
#pragma unroll
        for (int kc = 0; kc < 4; ++kc) {
            f16x4 af = *reinterpret_cast<const f16x4*>(&As[wr + il][kc * 8 + 4 * g]);
            f16x4 bf = *reinterpret_cast<const f16x4*>(&Bs[wc + il][kc * 8 + 4 * g]);
            acc = mfma8f16(af, bf, acc);
        }
    }

    const int colg = n0 + wc + il;
    if (MODE == 0) {
#pragma unroll
        for (int q = 0; q < 4; ++q) {
            const int row = m0 + wr + 8 * q + 4 * g;
            f16x4 v;
#pragma unroll
            for (int r = 0; r < 4; ++r) v[r] = (_Float16)acc[4 * q + r];
            *reinterpret_cast<f16x4*>(&outT[(size_t)colg * NN + row]) = v;
        }
    } else {
        const float bs = bias[colg];
#pragma unroll
        for (int reg = 0; reg < 16; ++reg) {
            const int row = m0 + wr + (reg & 3) + 8 * (reg >> 2) + 4 * g;
            float vv = acc[reg] + bs;
            if (MODE == 2) vv = 0.5f * vv * (1.0f + erff(vv * 0.70710678118f));
            outF[(size_t)row * CALL + colg] = vv;
        }
    }
}

// ---------------------------------------------------------------------------
// a_src[n][h] = sum_d h[n][h*32+d]*attn_src[h][d]; same for a_dst.
// Reads hT (transposed f16). grid 32, block 256: 64 n x 4 col-quarters(=3 heads)
// ---------------------------------------------------------------------------
__global__ __launch_bounds__(256) void srcdst_kernel(
    const _Float16* __restrict__ hT, const float* __restrict__ attn_src,
    const float* __restrict__ attn_dst, float* __restrict__ asrc, float* __restrict__ adst)
{
    __shared__ float ssrc[CALL], sdst[CALL];
    const int t = threadIdx.x;
    for (int idx = t; idx < CALL; idx += 256) { ssrc[idx] = attn_src[idx]; sdst[idx] = attn_dst[idx]; }
    __syncthreads();
    const int n = blockIdx.x * 64 + (t & 63);
    const int q = t >> 6;  // heads 3q..3q+2
#pragma unroll
    for (int hh = 0; hh < 3; ++hh) {
        float a0 = 0.f, a1 = 0.f;
        for (int dd = 0; dd < 32; ++dd) {
            const int c = q * 96 + hh * 32 + dd;
            const float v = (float)hT[(size_t)c * NN + n];
            a0 = fmaf(v, ssrc[c], a0);
            a1 = fmaf(v, sdst[c], a1);
        }
        asrc[n * NH + q * 3 + hh] = a0;
        adst[n * NH + q * 3 + hh] = a1;
    }
}

// ---------------------------------------------------------------------------
// Attention: per block = 32-row band x j-range. 4 waves x 3 heads.
// E[i][j] = mask(adj>0) * exp(leakyrelu(asrc_i + adst_j + adj_ij*eW + eb))
// numer[i][h*32+d] += E @ hT  (v_mfma_f32_32x32x8_f16), denom scalar sums.
// ---------------------------------------------------------------------------
__global__ __launch_bounds__(256) void attn_kernel(
    const float* __restrict__ adj, const _Float16* __restrict__ hT,
    const float* __restrict__ asrc, const float* __restrict__ adst,
    const float* __restrict__ eW, const float* __restrict__ eb,
    float* __restrict__ numer, float* __restrict__ denom, int JSZ)
{
    __shared__ float adj_s[32][65];
    __shared__ _Float16 hT_s[CALL][68];   // row stride 136B (8B-aligned, ~2-way banks)
    __shared__ float adst_s[64][NH];
    __shared__ float asrc_s[32][NH];

    const int t = threadIdx.x;
    const int w = t >> 6, l = t & 63, g = l >> 5, il = l & 31;
    const int band = blockIdx.x & 63, js = blockIdx.x >> 6;
    const int i0 = band * 32;
    const int j0 = js * JSZ;

    for (int idx = t; idx < 32 * NH; idx += 256)
        asrc_s[idx / NH][idx % NH] = asrc[(size_t)(i0 + idx / NH) * NH + idx % NH];
    __syncthreads();

    const int h0 = 3 * w;
    float asr[3], eWr[3], ebr[3];
#pragma unroll
    for (int hh = 0; hh < 3; ++hh) {
        asr[hh] = asrc_s[il][h0 + hh];
        eWr[hh] = eW[h0 + hh];
        ebr[hh] = eb[h0 + hh];
    }
    f32x16 acc[3];
#pragma unroll
    for (int hh = 0; hh < 3; ++hh)
#pragma unroll
        for (int r = 0; r < 16; ++r) acc[hh][r] = 0.f;
    float dsum[3] = {0.f, 0.f, 0.f};

    for (int jb = j0; jb < j0 + JSZ; jb += 64) {
        __syncthreads();
        {   // stage adj tile 32x64
            const int r = t >> 3, s8 = t & 7;
            const float* sp = adj + (size_t)(i0 + r) * NN + jb + s8 * 8;
            float4 v0 = *reinterpret_cast<const float4*>(sp);
            float4 v1 = *reinterpret_cast<const float4*>(sp + 4);
            float* dp = &adj_s[r][s8 * 8];
            dp[0] = v0.x; dp[1] = v0.y; dp[2] = v0.z; dp[3] = v0.w;
            dp[4] = v1.x; dp[5] = v1.y; dp[6] = v1.z; dp[7] = v1.w;
        }
        // stage adst chunk 64x12 (contiguous)
        for (int idx = t; idx < 64 * NH; idx += 256)
            (&adst_s[0][0])[idx] = adst[(size_t)jb * NH + idx];
        // stage hT tile 384x64
#pragma unroll
        for (int k = 0; k < 12; ++k) {
            const int sg = k * 256 + t;
            const int c = sg >> 3, s8 = sg & 7;
            const uint4 v = *reinterpret_cast<const uint4*>(hT + (size_t)c * NN + jb + s8 * 8);
            *reinterpret_cast<uint2*>(&hT_s[c][s8 * 8])     = make_uint2(v.x, v.y);
            *reinterpret_cast<uint2*>(&hT_s[c][s8 * 8 + 4]) = make_uint2(v.z, v.w);
        }
        __syncthreads();
#pragma unroll 2
        for (int ks = 0; ks < 8; ++ks) {
            float aj[4];
#pragma unroll
            for (int jj = 0; jj < 4; ++jj) aj[jj] = adj_s[il][ks * 8 + 4 * g + jj];
#pragma unroll
            for (int hh = 0; hh < 3; ++hh) {
                const int h = h0 + hh;
                f16x4 ef;
#pragma unroll
                for (int jj = 0; jj < 4; ++jj) {
                    const float ad_ = adst_s[ks * 8 + 4 * g + jj][h];
                    float tt = fmaf(aj[jj], eWr[hh], asr[hh] + ad_ + ebr[hh]);
                    tt = fmaxf(tt, 0.2f * tt);
                    const float ee = aj[jj] > 0.f ? exp2f(tt * 1.44269504089f) : 0.f;
                    dsum[hh] += ee;
                    ef[jj] = (_Float16)ee;
                }
                const f16x4 vf = *reinterpret_cast<const f16x4*>(&hT_s[h * 32 + il][ks * 8 + 4 * g]);
                acc[hh] = mfma8f16(ef, vf, acc[hh]);
            }
        }
    }

#pragma unroll
    for (int hh = 0; hh < 3; ++hh) {
        const int h = h0 + hh;
#pragma unroll
        for (int reg = 0; reg < 16; ++reg) {
            const int row = i0 + (reg & 3) + 8 * (reg >> 2) + 4 * g;
            numer[((size_t)js * NN + row) * CALL + h * 32 + il] = acc[hh][reg];
        }
        const float o = __shfl_xor(dsum[hh], 32);
        const float tot = dsum[hh] + o;
        if (l < 32) denom[((size_t)js * NN + i0 + il) * NH + h] = tot;
    }
}

// ---------------------------------------------------------------------------
// hsum = sum_js numer / sum_js denom + res  -> f16
// ---------------------------------------------------------------------------
__global__ __launch_bounds__(256) void reduce_kernel(
    const float* __restrict__ numer, const float* __restrict__ denom,
    const float* __restrict__ res, _Float16* __restrict__ hsum, int JS)
{
    const int idx = blockIdx.x * 256 + threadIdx.x;
    const int i = idx / CALL, c = idx % CALL, h = c >> 5;
    float s = 0.f, d = 0.f;
    for (int js = 0; js < JS; ++js) {
        s += numer[(size_t)js * NN * CALL + idx];
        d += denom[(size_t)js * NN * NH + (size_t)i * NH + h];
    }
    hsum[idx] = (_Float16)(s / d + res[idx]);
}

extern "C" void kernel_launch(void* const* d_in, const int* in_sizes, int n_in,
                              void* d_out, int out_size, void* d_ws, size_t ws_size,
                              hipStream_t stream)
{
    const float* x        = (const float*)d_in[0];
    const float* adj      = (const float*)d_in[1];
    const float* W        = (const float*)d_in[2];
    const float* attn_src = (const float*)d_in[3];
    const float* attn_dst = (const float*)d_in[4];
    const float* edge_W   = (const float*)d_in[5];
    const float* edge_b   = (const float*)d_in[6];
    const float* res_W    = (const float*)d_in[7];
    const float* res_b    = (const float*)d_in[8];
    const float* fus_W    = (const float*)d_in[9];
    const float* fus_b    = (const float*)d_in[10];
    float* out = (float*)d_out;

    char* ws = (char*)d_ws;
    size_t off = 0;
    auto alloc = [&](size_t bytes) { void* p = ws + off; off = (off + bytes + 255) & ~(size_t)255; return p; };
    _Float16* hT   = (_Float16*)alloc((size_t)CALL * NN * 2);
    float*    res  = (float*)alloc((size_t)NN * CALL * 4);
    float*    asrc = (float*)alloc((size_t)NN * NH * 4);
    float*    adst = (float*)alloc((size_t)NN * NH * 4);
    _Float16* hsum = (_Float16*)alloc((size_t)NN * CALL * 2);
    const size_t fixed = off;
    int JS = 8;
    while (JS > 1 && fixed + (size_t)JS * ((size_t)NN * CALL * 4 + (size_t)NN * NH * 4 + 512) > ws_size) JS >>= 1;
    float* numer = (float*)alloc((size_t)JS * NN * CALL * 4);
    float* denom = (float*)alloc((size_t)JS * NN * NH * 4);
    const int JSZ = NN / JS;

    dim3 blk(256);
    gemm_bt<0><<<dim3(32, 6), blk, 0, stream>>>(x, nullptr, W, nullptr, hT, nullptr, 256);
    gemm_bt<1><<<dim3(32, 6), blk, 0, stream>>>(x, nullptr, res_W, res_b, nullptr, res, 256);
    srcdst_kernel<<<32, blk, 0, stream>>>(hT, attn_src, attn_dst, asrc, adst);
    attn_kernel<<<64 * JS, blk, 0, stream>>>(adj, hT, asrc, adst, edge_W, edge_b, numer, denom, JSZ);
    reduce_kernel<<<NN * CALL / 256, blk, 0, stream>>>(numer, denom, res, hsum, JS);
    gemm_bt<2><<<dim3(32, 6), blk, 0, stream>>>(nullptr, hsum, fus_W, fus_b, nullptr, out, 384);
}

// Round 2
// 76.314 us; speedup vs baseline: 1.0196x; 1.0196x over previous
//
#include <hip/hip_runtime.h>
#include <hip/hip_bf16.h>

#define NN 2048
#define NH 12
#define HD 32
#define CALL 384   // NH*HD == OUT

typedef float f32x16 __attribute__((ext_vector_type(16)));
typedef _Float16 f16x4 __attribute__((ext_vector_type(4)));

static __device__ __forceinline__ f32x16 mfma8f16(f16x4 a, f16x4 b, f32x16 c) {
    return __builtin_amdgcn_mfma_f32_32x32x8f16(a, b, c, 0, 0, 0);
}

// ---------------------------------------------------------------------------
// GEMM-BT: out[m][n] = sum_k A[m][k] * B[n][k]   (both row-major, contract k)
// MODE 0: A=f32, write outT (f16, transposed [384][2048]), no bias   (h = x W^T)
// MODE 1: A=f32, write outF (f32 [M][384]) + bias                    (res)
// MODE 2: A=f16, write outF (f32 [M][384]) + bias + exact GELU       (final)
// ---------------------------------------------------------------------------
template <int MODE>
__global__ __launch_bounds__(256) void gemm_bt(
    const float* __restrict__ A, const _Float16* __restrict__ A16,
    const float* __restrict__ B, const float* __restrict__ bias,
    _Float16* __restrict__ outT, float* __restrict__ outF, int Kdim)
{
    __shared__ _Float16 As[64][36];
    __shared__ _Float16 Bs[64][36];
    const int t = threadIdx.x;
    const int w = t >> 6, l = t & 63, g = l >> 5, il = l & 31;
    const int m0 = blockIdx.x * 64, n0 = blockIdx.y * 64;
    const int wr = (w >> 1) * 32, wc = (w & 1) * 32;
    const int ti = t >> 2, seg = t & 3;

    f32x16 acc;
#pragma unroll
    for (int r = 0; r < 16; ++r) acc[r] = 0.f;

    for (int kk = 0; kk < Kdim; kk += 32) {
        __syncthreads();
        if (MODE == 2) {
            const uint4 v = *reinterpret_cast<const uint4*>(A16 + (size_t)(m0 + ti) * Kdim + kk + seg * 8);
            *reinterpret_cast<uint2*>(&As[ti][seg * 8])     = make_uint2(v.x, v.y);
            *reinterpret_cast<uint2*>(&As[ti][seg * 8 + 4]) = make_uint2(v.z, v.w);
        } else {
            const float* Ap = A + (size_t)(m0 + ti) * Kdim + kk + seg * 8;
            float4 v0 = *reinterpret_cast<const float4*>(Ap);
            float4 v1 = *reinterpret_cast<const float4*>(Ap + 4);
            f16x4 lo = {(_Float16)v0.x, (_Float16)v0.y, (_Float16)v0.z, (_Float16)v0.w};
            f16x4 hi = {(_Float16)v1.x, (_Float16)v1.y, (_Float16)v1.z, (_Float16)v1.w};
            *reinterpret_cast<f16x4*>(&As[ti][seg * 8])     = lo;
            *reinterpret_cast<f16x4*>(&As[ti][seg * 8 + 4]) = hi;
        }
        {
            const float* Bp = B + (size_t)(n0 + ti) * Kdim + kk + seg * 8;
            float4 v0 = *reinterpret_cast<const float4*>(Bp);
            float4 v1 = *reinterpret_cast<const float4*>(Bp + 4);
            f16x4 lo = {(_Float16)v0.x, (_Float16)v0.y, (_Float16)v0.z, (_Float16)v0.w};
            f16x4 hi = {(_Float16)v1.x, (_Float16)v1.y, (_Float16)v1.z, (_Float16)v1.w};
            *reinterpret_cast<f16x4*>(&Bs[ti][seg * 8])     = lo;
            *reinterpret_cast<f16x4*>(&Bs[ti][seg * 8 + 4]) = hi;
        }
        __syncthreads();
#pragma unroll
        for (int kc = 0; kc < 4; ++kc) {
            f16x4 af = *reinterpret_cast<const f16x4*>(&As[wr + il][kc * 8 + 4 * g]);
            f16x4 bf = *reinterpret_cast<const f16x4*>(&Bs[wc + il][kc * 8 + 4 * g]);
            acc = mfma8f16(af, bf, acc);
        }
    }

    const int colg = n0 + wc + il;
    if (MODE == 0) {
#pragma unroll
        for (int q = 0; q < 4; ++q) {
            const int row = m0 + wr + 8 * q + 4 * g;
            f16x4 v;
#pragma unroll
            for (int r = 0; r < 4; ++r) v[r] = (_Float16)acc[4 * q + r];
            *reinterpret_cast<f16x4*>(&outT[(size_t)colg * NN + row]) = v;
        }
    } else {
        const float bs = bias[colg];
#pragma unroll
        for (int reg = 0; reg < 16; ++reg) {
            const int row = m0 + wr + (reg & 3) + 8 * (reg >> 2) + 4 * g;
            float vv = acc[reg] + bs;
            if (MODE == 2) vv = 0.5f * vv * (1.0f + erff(vv * 0.70710678118f));
            outF[(size_t)row * CALL + colg] = vv;
        }
    }
}

// ---------------------------------------------------------------------------
// a_src[n][h] (row-major) and a_dstT[h][n] (transposed for attn staging)
// ---------------------------------------------------------------------------
__global__ __launch_bounds__(256) void srcdst_kernel(
    const _Float16* __restrict__ hT, const float* __restrict__ attn_src,
    const float* __restrict__ attn_dst, float* __restrict__ asrc, float* __restrict__ adstT)
{
    __shared__ float ssrc[CALL], sdst[CALL];
    const int t = threadIdx.x;
    for (int idx = t; idx < CALL; idx += 256) { ssrc[idx] = attn_src[idx]; sdst[idx] = attn_dst[idx]; }
    __syncthreads();
    const int n = blockIdx.x * 64 + (t & 63);
    const int q = t >> 6;  // heads 3q..3q+2
#pragma unroll
    for (int hh = 0; hh < 3; ++hh) {
        float a0 = 0.f, a1 = 0.f;
        for (int dd = 0; dd < 32; ++dd) {
            const int c = q * 96 + hh * 32 + dd;
            const float v = (float)hT[(size_t)c * NN + n];
            a0 = fmaf(v, ssrc[c], a0);
            a1 = fmaf(v, sdst[c], a1);
        }
        asrc[n * NH + q * 3 + hh] = a0;
        adstT[(size_t)(q * 3 + hh) * NN + n] = a1;
    }
}

// ---------------------------------------------------------------------------
// attn2: block = 32-row band x 3 heads. 8 waves, each owns a 256-col j-chunk.
// Per-wave private LDS staging (adj 32x32, hT 96x32 f16, adstT 3x32).
// Cross-wave reduction via LDS (phase-overlapped region), then /denom + res
// -> hsum (f16). No global partials.
// ---------------------------------------------------------------------------
__global__ __launch_bounds__(512, 2) void attn2(
    const float* __restrict__ adj, const _Float16* __restrict__ hT,
    const float* __restrict__ asrc, const float* __restrict__ adstT,
    const float* __restrict__ eW, const float* __restrict__ eb,
    const float* __restrict__ res, _Float16* __restrict__ hsum)
{
    // layout: per-wave slice w*11904: adj[32][36] f32 (4608B) | hT[96][36] f16 (6912B) | adst[3][32] f32 (384B)
    // phase 2 (after barrier): red[8*3][16][64] f32 = 98304B overlaps slices; dsum at 98304 (3072B) persistent.
    __shared__ __align__(16) char smem[101376];
    const int t = threadIdx.x;
    const int w = t >> 6, l = t & 63, g = l >> 5, il = l & 31;
    const int band = blockIdx.x & 63, hg = blockIdx.x >> 6;
    const int i0 = band * 32, h0 = hg * 3, c0 = hg * 96;

    float (*adj_s)[36]   = (float(*)[36])(smem + w * 11904);
    _Float16 (*hT_s)[36] = (_Float16(*)[36])(smem + w * 11904 + 4608);
    float (*adst_s)[32]  = (float(*)[32])(smem + w * 11904 + 11520);
    float* red    = (float*)smem;
    float* dsum_s = (float*)(smem + 98304);

    float asr[3], eWr[3], ebr[3];
#pragma unroll
    for (int hh = 0; hh < 3; ++hh) {
        asr[hh] = asrc[(size_t)(i0 + il) * NH + h0 + hh];
        eWr[hh] = eW[h0 + hh];
        ebr[hh] = eb[h0 + hh];
    }
    f32x16 acc[3];
#pragma unroll
    for (int hh = 0; hh < 3; ++hh)
#pragma unroll
        for (int r = 0; r < 16; ++r) acc[hh][r] = 0.f;
    float dsum[3] = {0.f, 0.f, 0.f};

    const int jbase = w * 256;
    for (int tile = 0; tile < 8; ++tile) {
        const int jb = jbase + tile * 32;
        __syncthreads();
        // stage adj 32x32 (4x float4 per lane)
#pragma unroll
        for (int p = 0; p < 4; ++p) {
            const int idx = p * 64 + l;
            const int r = idx >> 3, c4 = (idx & 7) * 4;
            *reinterpret_cast<float4*>(&adj_s[r][c4]) =
                *reinterpret_cast<const float4*>(adj + (size_t)(i0 + r) * NN + jb + c4);
        }
        // stage hT 96x32 f16
#pragma unroll
        for (int p = 0; p < 6; ++p) {
            const int r = p * 16 + (l >> 2), s = (l & 3) * 8;
            const uint4 v = *reinterpret_cast<const uint4*>(hT + (size_t)(c0 + r) * NN + jb + s);
            *reinterpret_cast<uint2*>(&hT_s[r][s])     = make_uint2(v.x, v.y);
            *reinterpret_cast<uint2*>(&hT_s[r][s + 4]) = make_uint2(v.z, v.w);
        }
        // stage adstT 3x32
        adst_s[l >> 5][l & 31] = adstT[(size_t)(h0 + (l >> 5)) * NN + jb + (l & 31)];
        if (l < 32) adst_s[2][l] = adstT[(size_t)(h0 + 2) * NN + jb + l];
        __syncthreads();

#pragma unroll
        for (int ks = 0; ks < 4; ++ks) {
            const float4 aj = *reinterpret_cast<const float4*>(&adj_s[il][ks * 8 + 4 * g]);
#pragma unroll
            for (int hh = 0; hh < 3; ++hh) {
                f16x4 ef;
#pragma unroll
                for (int jj = 0; jj < 4; ++jj) {
                    const float ajv = (&aj.x)[jj];
                    const float ad_ = adst_s[hh][ks * 8 + 4 * g + jj];
                    float tt = fmaf(ajv, eWr[hh], asr[hh] + ad_ + ebr[hh]);
                    tt = fmaxf(tt, 0.2f * tt);
                    const float ee = ajv > 0.f ? exp2f(tt * 1.44269504089f) : 0.f;
                    dsum[hh] += ee;
                    ef[jj] = (_Float16)ee;
                }
                const f16x4 vf = *reinterpret_cast<const f16x4*>(&hT_s[hh * 32 + il][ks * 8 + 4 * g]);
                acc[hh] = mfma8f16(ef, vf, acc[hh]);
            }
        }
    }

    __syncthreads();   // all staging reads done; red region may now overwrite slices
#pragma unroll
    for (int hh = 0; hh < 3; ++hh) {
        const float dtot = dsum[hh] + __shfl_xor(dsum[hh], 32);
        if (g == 0) dsum_s[(w * 3 + hh) * 32 + il] = dtot;
#pragma unroll
        for (int reg = 0; reg < 16; ++reg)
            red[((w * 3 + hh) * 16 + reg) * 64 + l] = acc[hh][reg];
    }
    __syncthreads();

#pragma unroll
    for (int rr = 0; rr < 2; ++rr) {
        const int reg = w + rr * 8;
        const int row_off = (reg & 3) + 8 * (reg >> 2) + 4 * g;
        const int row = i0 + row_off;
#pragma unroll
        for (int hh = 0; hh < 3; ++hh) {
            float v = 0.f, d = 0.f;
#pragma unroll
            for (int ww = 0; ww < 8; ++ww) {
                v += red[((ww * 3 + hh) * 16 + reg) * 64 + l];
                d += dsum_s[(ww * 3 + hh) * 32 + row_off];
            }
            const int col = (h0 + hh) * 32 + il;
            hsum[(size_t)row * CALL + col] = (_Float16)(v / d + res[(size_t)row * CALL + col]);
        }
    }
}

extern "C" void kernel_launch(void* const* d_in, const int* in_sizes, int n_in,
                              void* d_out, int out_size, void* d_ws, size_t ws_size,
                              hipStream_t stream)
{
    const float* x        = (const float*)d_in[0];
    const float* adj      = (const float*)d_in[1];
    const float* W        = (const float*)d_in[2];
    const float* attn_src = (const float*)d_in[3];
    const float* attn_dst = (const float*)d_in[4];
    const float* edge_W   = (const float*)d_in[5];
    const float* edge_b   = (const float*)d_in[6];
    const float* res_W    = (const float*)d_in[7];
    const float* res_b    = (const float*)d_in[8];
    const float* fus_W    = (const float*)d_in[9];
    const float* fus_b    = (const float*)d_in[10];
    float* out = (float*)d_out;

    char* ws = (char*)d_ws;
    size_t off = 0;
    auto alloc = [&](size_t bytes) { void* p = ws + off; off = (off + bytes + 255) & ~(size_t)255; return p; };
    _Float16* hT    = (_Float16*)alloc((size_t)CALL * NN * 2);
    float*    res   = (float*)alloc((size_t)NN * CALL * 4);
    float*    asrc  = (float*)alloc((size_t)NN * NH * 4);
    float*    adstT = (float*)alloc((size_t)NH * NN * 4);
    _Float16* hsum  = (_Float16*)alloc((size_t)NN * CALL * 2);
    (void)ws_size;

    dim3 blk(256);
    gemm_bt<0><<<dim3(32, 6), blk, 0, stream>>>(x, nullptr, W, nullptr, hT, nullptr, 256);
    gemm_bt<1><<<dim3(32, 6), blk, 0, stream>>>(x, nullptr, res_W, res_b, nullptr, res, 256);
    srcdst_kernel<<<32, blk, 0, stream>>>(hT, attn_src, attn_dst, asrc, adstT);
    attn2<<<256, dim3(512), 0, stream>>>(adj, hT, asrc, adstT, edge_W, edge_b, res, hsum);
    gemm_bt<2><<<dim3(32, 6), blk, 0, stream>>>(nullptr, hsum, fus_W, fus_b, nullptr, out, 384);
}